// Round 7
// baseline (612.155 us; speedup 1.0000x reference)
//
#include <hip/hip_runtime.h>

#define GD 130              // grid extent per dim (G+2)
#define GD2 (GD*GD)
#define GRID_ELEMS (GD*GD*GD)
#define STATS_BYTES 1024
#define CHUNK 64            // consecutive rows per wave chunk
#define RB 4                // rows per probe batch (2 masks x 54 lanes)
#define WPB 16              // waves per conv block (1024 threads)
#define CONV_BLOCKS 256
#define MAX_NIN 100000
#define MAX_NOUT 1600000
#define WSTRIDE 5           // padded granule stride (conflict-free, R5-verified)

typedef _Float16 h2 __attribute__((ext_vector_type(2)));

__device__ _Float16 g_feat16[MAX_NIN * 32];            // 6.4 MB
__device__ _Float16 g_out16[(size_t)MAX_NOUT * 64];    // 204.8 MB intermediate

__device__ __forceinline__ float dot2(unsigned int f, unsigned int w, float acc) {
    union { unsigned int u; h2 h; } a, b;
    a.u = f; b.u = w;
    return __builtin_amdgcn_fdot2(a.h, b.h, acc, false);
}

__global__ __launch_bounds__(256) void scatter_grid_k(
    const int* __restrict__ pos, int* __restrict__ grid, int n_in)
{
    int i = blockIdx.x * blockDim.x + threadIdx.x;
    if (i < n_in) {
        int x = pos[3*i], y = pos[3*i+1], z = pos[3*i+2];
        grid[(x*GD + y)*GD + z] = i;
    }
}

__global__ __launch_bounds__(256) void feat_to_f16_k(
    const float* __restrict__ feat, int n32)
{
    int i = (blockIdx.x * blockDim.x + threadIdx.x) * 8;
    if (i < n32) {
        const float4 a = *reinterpret_cast<const float4*>(feat + i);
        const float4 b = *reinterpret_cast<const float4*>(feat + i + 4);
        union { _Float16 h[8]; uint4 u; } t;
        t.h[0] = (_Float16)a.x; t.h[1] = (_Float16)a.y;
        t.h[2] = (_Float16)a.z; t.h[3] = (_Float16)a.w;
        t.h[4] = (_Float16)b.x; t.h[5] = (_Float16)b.y;
        t.h[6] = (_Float16)b.z; t.h[7] = (_Float16)b.w;
        *reinterpret_cast<uint4*>(g_feat16 + i) = t.u;
    }
}

// pop lowest set bit of M; load that tap's feat row (4 uint4, stays in flight)
#define POP_ISSUE(S, M, IV, T, F0, F1, F2, F3)                                \
    S = -1;                                                                   \
    if (M) {                                                                  \
        S = (int)__builtin_ctzll(M); M &= M - 1;                              \
        T = (S >= 27) ? S - 27 : S;                                           \
        const int _idx = __builtin_amdgcn_readlane(IV, S);                    \
        const uint4* _fp = reinterpret_cast<const uint4*>(                    \
            g_feat16 + (size_t)_idx * 32);                                    \
        F0 = _fp[0]; F1 = _fp[1]; F2 = _fp[2]; F3 = _fp[3];                   \
    }

#define FLUSH(R, A0, A1) {                                                    \
    const float _a = (A0) + (A1);                                             \
    g_out16[(size_t)(R) * 64 + lane] = (_Float16)_a;                          \
    ssum += _a; ssq = fmaf(_a, _a, ssq); }

#define COMPUTE(S, T, F0, F1, F2, F3, ROWBASE, CURR, A0, A1)                  \
    if (S >= 0) {                                                             \
        const int _row = (ROWBASE) + ((S >= 27) ? 1 : 0);                     \
        if (_row != CURR) {                                                   \
            if (CURR >= 0) FLUSH(CURR, A0, A1);                               \
            CURR = _row; A0 = 0.f; A1 = 0.f;                                  \
        }                                                                     \
        const uint4* _wr = wlds + ((T)*64 + lane) * WSTRIDE;                  \
        const uint4 _w0 = _wr[0], _w1 = _wr[1], _w2 = _wr[2], _w3 = _wr[3];   \
        A0 = dot2(F0.x, _w0.x, A0); A1 = dot2(F0.y, _w0.y, A1);               \
        A0 = dot2(F0.z, _w0.z, A0); A1 = dot2(F0.w, _w0.w, A1);               \
        A0 = dot2(F1.x, _w1.x, A0); A1 = dot2(F1.y, _w1.y, A1);               \
        A0 = dot2(F1.z, _w1.z, A0); A1 = dot2(F1.w, _w1.w, A1);               \
        A0 = dot2(F2.x, _w2.x, A0); A1 = dot2(F2.y, _w2.y, A1);               \
        A0 = dot2(F2.z, _w2.z, A0); A1 = dot2(F2.w, _w2.w, A1);               \
        A0 = dot2(F3.x, _w3.x, A0); A1 = dot2(F3.y, _w3.y, A1);               \
        A0 = dot2(F3.z, _w3.z, A0); A1 = dot2(F3.w, _w3.w, A1);               \
    }

__global__ __launch_bounds__(1024, 4) void conv_stats_k(
    const float* __restrict__ W,
    const int* __restrict__ outpos, const int* __restrict__ grid,
    float* __restrict__ stats, int n_out)
{
    __shared__ uint4 wlds[27*64*WSTRIDE];   // 138,240 B
    __shared__ float sstat[128];

    const int tid  = threadIdx.x;
    const int lane = tid & 63;
    const int wid  = tid >> 6;

    // stage W: global [k][cin][cout] f32 -> LDS [k][cout][granule] f16
    for (int g = tid; g < 27*64*4; g += 1024) {
        const int k   = g >> 8;
        const int rem = g & 255;
        const int o   = rem >> 2;
        const int q   = rem & 3;
        union { _Float16 h[8]; uint4 u; } t;
        #pragma unroll
        for (int j = 0; j < 8; ++j)
            t.h[j] = (_Float16)W[k*2048 + (q*8 + j)*64 + o];
        wlds[(k*64 + o)*WSTRIDE + q] = t.u;
    }
    if (tid < 128) sstat[tid] = 0.f;
    __syncthreads();

    // lane -> (local row half, tap): lanes 0..26 row+0, 27..53 row+1
    const int rloc = (lane >= 27) ? 1 : 0;
    const int tap  = lane - 27 * rloc;
    const bool lv  = (lane < 54);
    const int dx   = tap / 9, dyz = tap - 9*dx;
    const int dy   = dyz / 3, dz = dyz - 3*dy;
    const int cOff = dx*GD2 + dy*GD + dz;

    // probe 4 rows starting at row0: stream A = rows row0..row0+1, B = +2..+3
    auto probe = [&](int row0, int& iA, int& iB) {
        const int rowA = row0 + rloc;
        const int rowB = row0 + 2 + rloc;
        const int raC = min(rowA, n_out - 1);
        const int rbC = min(rowB, n_out - 1);
        const int xA = outpos[3*raC], yA = outpos[3*raC+1], zA = outpos[3*raC+2];
        const int xB = outpos[3*rbC], yB = outpos[3*rbC+1], zB = outpos[3*rbC+2];
        int a = grid[(xA*GD + yA)*GD + zA + cOff];
        int b = grid[(xB*GD + yB)*GD + zB + cOff];
        if (!lv || rowA >= n_out) a = -1;
        if (!lv || rowB >= n_out) b = -1;
        iA = a; iB = b;
    };

    const int gw = blockIdx.x * WPB + wid;
    const int nw = gridDim.x * WPB;
    const int nchunks = (n_out + CHUNK - 1) / CHUNK;
    const int NB = CHUNK / RB;

    float ssum = 0.f, ssq = 0.f;

    for (int ch = gw; ch < nchunks; ch += nw) {
        const int rbase = ch * CHUNK;
        int iA_c, iB_c;
        probe(rbase, iA_c, iB_c);

        for (int b = 0; b < NB; ++b) {
            const int row0 = rbase + b * RB;
            if (row0 >= n_out) break;

            unsigned long long mA = __ballot(iA_c >= 0);
            unsigned long long mB = __ballot(iB_c >= 0);

            // prefetch next batch's probes (hides outpos->grid chain)
            int iA_n = -1, iB_n = -1;
            const int row0n = row0 + RB;
            if (b + 1 < NB && row0n < n_out) probe(row0n, iA_n, iB_n);

            int curA = -1, curB = -1;
            float aA0 = 0.f, aA1 = 0.f, aB0 = 0.f, aB1 = 0.f;

            int sA0, tA0, sB0, tB0, sA1, tA1, sB1, tB1;
            uint4 fA00, fA01, fA02, fA03, fB00, fB01, fB02, fB03;
            uint4 fA10, fA11, fA12, fA13, fB10, fB11, fB12, fB13;

            POP_ISSUE(sA0, mA, iA_c, tA0, fA00, fA01, fA02, fA03)
            POP_ISSUE(sB0, mB, iB_c, tB0, fB00, fB01, fB02, fB03)

            for (;;) {
                if (sA0 < 0 && sB0 < 0) break;
                POP_ISSUE(sA1, mA, iA_c, tA1, fA10, fA11, fA12, fA13)
                POP_ISSUE(sB1, mB, iB_c, tB1, fB10, fB11, fB12, fB13)
                COMPUTE(sA0, tA0, fA00, fA01, fA02, fA03, row0,     curA, aA0, aA1)
                COMPUTE(sB0, tB0, fB00, fB01, fB02, fB03, row0 + 2, curB, aB0, aB1)
                if (sA1 < 0 && sB1 < 0) break;
                POP_ISSUE(sA0, mA, iA_c, tA0, fA00, fA01, fA02, fA03)
                POP_ISSUE(sB0, mB, iB_c, tB0, fB00, fB01, fB02, fB03)
                COMPUTE(sA1, tA1, fA10, fA11, fA12, fA13, row0,     curA, aA0, aA1)
                COMPUTE(sB1, tB1, fB10, fB11, fB12, fB13, row0 + 2, curB, aB0, aB1)
            }
            if (curA >= 0) FLUSH(curA, aA0, aA1)
            if (curB >= 0) FLUSH(curB, aB0, aB1)

            iA_c = iA_n; iB_c = iB_n;
        }
    }

    atomicAdd(&sstat[lane],      ssum);
    atomicAdd(&sstat[64 + lane], ssq);
    __syncthreads();
    if (tid < 128) unsafeAtomicAdd(&stats[tid], sstat[tid]);
}

__global__ __launch_bounds__(256) void bn_relu_k(
    float* __restrict__ out, const float* __restrict__ stats,
    const float* __restrict__ gamma, const float* __restrict__ beta, int n_out)
{
    __shared__ float sc[64], sh[64];
    if (threadIdx.x < 64) {
        const int c = threadIdx.x;
        const double inv_n = 1.0 / (double)n_out;
        const double mean = (double)stats[c] * inv_n;
        const double var  = (double)stats[64 + c] * inv_n - mean * mean;
        const float scale = gamma[c] * rsqrtf((float)var + 1e-5f);
        sc[c] = scale;
        sh[c] = beta[c] - (float)mean * scale;
    }
    __syncthreads();

    const size_t total8 = (size_t)n_out * 8;    // 8 halves per thread-iter
    for (size_t t = (size_t)blockIdx.x * blockDim.x + threadIdx.x;
         t < total8; t += (size_t)gridDim.x * blockDim.x) {
        union { uint4 u; _Float16 h[8]; } v;
        v.u = *reinterpret_cast<const uint4*>(g_out16 + t * 8);
        const int c0 = ((int)(t & 7)) * 8;
        float4 r0, r1;
        r0.x = fmaxf(fmaf((float)v.h[0], sc[c0+0], sh[c0+0]), 0.f);
        r0.y = fmaxf(fmaf((float)v.h[1], sc[c0+1], sh[c0+1]), 0.f);
        r0.z = fmaxf(fmaf((float)v.h[2], sc[c0+2], sh[c0+2]), 0.f);
        r0.w = fmaxf(fmaf((float)v.h[3], sc[c0+3], sh[c0+3]), 0.f);
        r1.x = fmaxf(fmaf((float)v.h[4], sc[c0+4], sh[c0+4]), 0.f);
        r1.y = fmaxf(fmaf((float)v.h[5], sc[c0+5], sh[c0+5]), 0.f);
        r1.z = fmaxf(fmaf((float)v.h[6], sc[c0+6], sh[c0+6]), 0.f);
        r1.w = fmaxf(fmaf((float)v.h[7], sc[c0+7], sh[c0+7]), 0.f);
        float4* o4 = reinterpret_cast<float4*>(out + t * 8);
        o4[0] = r0;
        o4[1] = r1;
    }
}

extern "C" void kernel_launch(void* const* d_in, const int* in_sizes, int n_in_arrs,
                              void* d_out, int out_size, void* d_ws, size_t ws_size,
                              hipStream_t stream)
{
    const float* feat   = (const float*)d_in[0];
    const float* W      = (const float*)d_in[1];
    const float* gamma  = (const float*)d_in[2];
    const float* beta   = (const float*)d_in[3];
    const int*   pos    = (const int*)d_in[4];
    const int*   outpos = (const int*)d_in[5];

    const int n_in  = in_sizes[0] / 32;
    const int n_out = in_sizes[5] / 3;

    float* out   = (float*)d_out;
    float* stats = (float*)d_ws;
    int*   grid  = (int*)((char*)d_ws + STATS_BYTES);

    hipMemsetAsync(stats, 0, STATS_BYTES, stream);
    hipMemsetAsync(grid, 0xFF, (size_t)GRID_ELEMS * 4, stream);   // int -1

    scatter_grid_k<<<(n_in + 255) / 256, 256, 0, stream>>>(pos, grid, n_in);
    feat_to_f16_k<<<(n_in * 32 / 8 + 255) / 256, 256, 0, stream>>>(feat, n_in * 32);
    conv_stats_k<<<CONV_BLOCKS, 1024, 0, stream>>>(W, outpos, grid, stats, n_out);
    bn_relu_k<<<2048, 256, 0, stream>>>(out, stats, gamma, beta, n_out);
}